// Round 1
// baseline (281.021 us; speedup 1.0000x reference)
//
#include <hip/hip_runtime.h>
#include <math.h>

#define EPS 1e-6f

// ---------------------------------------------------------------------------
// GEMM: C[m][d] = sum_{k<64} A[m*64+k] * W[d*ldw + c0 + k],  d in [0,64)
// A: [M x 64] row-major, W: [64 x ldw] row-major (we use a 64-col slice at c0)
// ---------------------------------------------------------------------------
__global__ __launch_bounds__(256) void gemm_nt64(
    const float* __restrict__ A, int M,
    const float* __restrict__ W, int ldw, int c0,
    float* __restrict__ C)
{
    __shared__ float As[64][68];
    __shared__ float Ws[64][68];
    const int tid = threadIdx.x;
    const int r0 = blockIdx.x * 64;

    // stage A tile (64 rows x 64 cols) as float4
    for (int t = tid; t < 1024; t += 256) {
        int r = t >> 4, c4 = (t & 15) << 2;
        float4 v = make_float4(0.f, 0.f, 0.f, 0.f);
        if (r0 + r < M)
            v = *reinterpret_cast<const float4*>(A + (size_t)(r0 + r) * 64 + c4);
        *reinterpret_cast<float4*>(&As[r][c4]) = v;
    }
    // stage W slice (64 rows x 64 cols)
    for (int t = tid; t < 1024; t += 256) {
        int d = t >> 4, c4 = (t & 15) << 2;
        float4 v = *reinterpret_cast<const float4*>(W + (size_t)d * ldw + c0 + c4);
        *reinterpret_cast<float4*>(&Ws[d][c4]) = v;
    }
    __syncthreads();

    const int ti = tid >> 4;   // 0..15 (row direction)
    const int tj = tid & 15;   // 0..15 (col direction)
    float acc[4][4];
#pragma unroll
    for (int i = 0; i < 4; ++i)
#pragma unroll
        for (int j = 0; j < 4; ++j) acc[i][j] = 0.f;

#pragma unroll
    for (int k = 0; k < 64; k += 4) {
        float4 a[4], w[4];
#pragma unroll
        for (int i = 0; i < 4; ++i)
            a[i] = *reinterpret_cast<const float4*>(&As[ti + 16 * i][k]);
#pragma unroll
        for (int j = 0; j < 4; ++j)
            w[j] = *reinterpret_cast<const float4*>(&Ws[tj + 16 * j][k]);
#pragma unroll
        for (int i = 0; i < 4; ++i)
#pragma unroll
            for (int j = 0; j < 4; ++j) {
                acc[i][j] += a[i].x * w[j].x;
                acc[i][j] += a[i].y * w[j].y;
                acc[i][j] += a[i].z * w[j].z;
                acc[i][j] += a[i].w * w[j].w;
            }
    }
#pragma unroll
    for (int i = 0; i < 4; ++i) {
        int r = r0 + ti + 16 * i;
        if (r < M) {
#pragma unroll
            for (int j = 0; j < 4; ++j)
                C[(size_t)r * 64 + tj + 16 * j] = acc[i][j];
        }
    }
}

// ---------------------------------------------------------------------------
// CSR build: histogram, scan (3 small kernels), placement
// ---------------------------------------------------------------------------
__global__ __launch_bounds__(256) void hist_kernel(const int* __restrict__ tail, int E,
                                                   int* __restrict__ deg)
{
    int e = blockIdx.x * 256 + threadIdx.x;
    if (e < E) atomicAdd(&deg[tail[e]], 1);
}

__global__ __launch_bounds__(256) void scan_chunk(const int* __restrict__ deg, int n,
                                                  int* __restrict__ incl, int* __restrict__ bsums)
{
    __shared__ int s[256];
    int tid = threadIdx.x;
    int i = blockIdx.x * 256 + tid;
    int v = (i < n) ? deg[i] : 0;
    int acc = v;
    s[tid] = acc;
    __syncthreads();
#pragma unroll
    for (int off = 1; off < 256; off <<= 1) {
        int add = (tid >= off) ? s[tid - off] : 0;
        __syncthreads();
        acc += add;
        s[tid] = acc;
        __syncthreads();
    }
    if (i < n) incl[i] = acc;
    if (tid == 255) bsums[blockIdx.x] = acc;
}

__global__ __launch_bounds__(256) void scan_tops(int* __restrict__ bsums, int nb)
{
    __shared__ int s[256];
    int tid = threadIdx.x;
    int v = (tid < nb) ? bsums[tid] : 0;
    int acc = v;
    s[tid] = acc;
    __syncthreads();
#pragma unroll
    for (int off = 1; off < 256; off <<= 1) {
        int add = (tid >= off) ? s[tid - off] : 0;
        __syncthreads();
        acc += add;
        s[tid] = acc;
        __syncthreads();
    }
    if (tid < nb) bsums[tid] = acc - v;   // exclusive scan of block sums
}

__global__ __launch_bounds__(256) void scan_final(const int* __restrict__ deg,
                                                  const int* __restrict__ incl,
                                                  const int* __restrict__ bsums, int n,
                                                  int* __restrict__ off, int* __restrict__ cursor)
{
    int i = blockIdx.x * 256 + threadIdx.x;
    if (i < n) {
        int e = incl[i] - deg[i] + bsums[blockIdx.x];
        off[i] = e;
        cursor[i] = e;
    }
}

__global__ __launch_bounds__(256) void place_kernel(const int* __restrict__ head,
                                                    const int* __restrict__ tail,
                                                    const int* __restrict__ rel, int E,
                                                    int* __restrict__ cursor,
                                                    unsigned int* __restrict__ shr)
{
    int e = blockIdx.x * 256 + threadIdx.x;
    if (e < E) {
        int t = tail[e];
        int p = atomicAdd(&cursor[t], 1);
        shr[p] = ((unsigned int)head[e] << 8) | (unsigned int)rel[e];  // h<2^24, r<256
    }
}

// ---------------------------------------------------------------------------
// Main: one wave per node. lane = output dim (64). Online softmax over the
// node's incoming edges + self-loop; 4 table-row gathers per edge, 1-deep
// software prefetch; 8-lane shfl_xor butterfly for per-head logit reduce.
// ---------------------------------------------------------------------------
__global__ __launch_bounds__(256) void ingram_main(
    const float* __restrict__ Pt, const float* __restrict__ Ph,
    const float* __restrict__ Qh, const float* __restrict__ Pr,
    const float* __restrict__ Qr,
    const int* __restrict__ deg, const int* __restrict__ off,
    const unsigned int* __restrict__ shr,
    const float* __restrict__ attn_b, const float* __restrict__ attn_vec,
    const float* __restrict__ aggr_b,
    float* __restrict__ out, int N)
{
    const int lane = threadIdx.x & 63;
    const int node = blockIdx.x * 4 + (threadIdx.x >> 6);
    if (node >= N) return;

    const float bA  = attn_b[lane];
    const float bG  = aggr_b[lane];
    const float vec = attn_vec[lane];          // [1,8,8] flat == per-dim weight
    const float ptd = Pt[(size_t)node * 64 + lane];

    const int start = off[node];
    const int dg    = deg[node];

    float m = -INFINITY, S = 0.f, O = 0.f, SP = 0.f, SQ = 0.f;

    for (int cstart = 0; cstart < dg; cstart += 64) {
        int nc = min(64, dg - cstart);
        unsigned int pk = 0u;
        if (lane < nc) pk = shr[start + cstart + lane];

        unsigned int p0 = (unsigned int)__shfl((int)pk, 0);
        int hh = (int)(p0 >> 8), rr = (int)(p0 & 255u);
        float ph = Ph[(size_t)hh * 64 + lane];
        float pr = Pr[rr * 64 + lane];
        float qh = Qh[(size_t)hh * 64 + lane];
        float qr = Qr[rr * 64 + lane];

        for (int j = 0; j < nc; ++j) {
            float phc = ph, prc = pr, qhc = qh, qrc = qr;
            if (j + 1 < nc) {
                unsigned int pn = (unsigned int)__shfl((int)pk, j + 1);
                int h2 = (int)(pn >> 8), r2 = (int)(pn & 255u);
                ph = Ph[(size_t)h2 * 64 + lane];
                pr = Pr[r2 * 64 + lane];
                qh = Qh[(size_t)h2 * 64 + lane];
                qr = Qr[r2 * 64 + lane];
            }
            SP += prc;
            SQ += qrc;
            float pre = ptd + phc + prc + bA;
            float a   = pre > 0.f ? pre : 0.2f * pre;   // leaky_relu 0.2
            float t   = a * vec;
            t += __shfl_xor(t, 1);
            t += __shfl_xor(t, 2);
            t += __shfl_xor(t, 4);                      // per-head logit, uniform in 8-lane group
            float Ad = qhc + qrc + bG;
            float mn = fmaxf(m, t);
            float sc = __expf(m - mn);                  // exp(-inf)=0 on first edge
            float av = __expf(t - mn);
            S = S * sc + av;
            O = O * sc + av * Ad;
            m = mn;
        }
    }

    // self-loop edge: rel = (sum of incoming P_r/Q_r) / (deg + eps)
    {
        float inv = 1.f / ((float)dg + EPS);
        float pre = ptd + Ph[(size_t)node * 64 + lane] + SP * inv + bA;
        float a   = pre > 0.f ? pre : 0.2f * pre;
        float t   = a * vec;
        t += __shfl_xor(t, 1);
        t += __shfl_xor(t, 2);
        t += __shfl_xor(t, 4);
        float Ad = Qh[(size_t)node * 64 + lane] + SQ * inv + bG;
        float mn = fmaxf(m, t);
        float sc = __expf(m - mn);
        float av = __expf(t - mn);
        S = S * sc + av;
        O = O * sc + av * Ad;
    }

    out[(size_t)node * 64 + lane] = O / (S + EPS);
}

// ---------------------------------------------------------------------------
extern "C" void kernel_launch(void* const* d_in, const int* in_sizes, int n_in,
                              void* d_out, int out_size, void* d_ws, size_t ws_size,
                              hipStream_t stream)
{
    const float* emb_ent  = (const float*)d_in[0];
    const float* emb_rel  = (const float*)d_in[1];
    const float* attn_W   = (const float*)d_in[2];   // [64 x 192]
    const float* attn_b   = (const float*)d_in[3];
    const float* attn_vec = (const float*)d_in[4];   // [1,8,8] -> 64
    const float* aggr_W   = (const float*)d_in[5];   // [64 x 128]
    const float* aggr_b   = (const float*)d_in[6];
    const int*   head     = (const int*)d_in[7];
    const int*   tail     = (const int*)d_in[8];
    const int*   rel      = (const int*)d_in[9];

    const int N = in_sizes[0] / 64;
    const int R = in_sizes[1] / 64;
    const int E = in_sizes[7];

    // workspace carve-up (~43 MB total)
    char* w = (char*)d_ws;
    float* Pt = (float*)w;            w += (size_t)N * 64 * sizeof(float);
    float* Ph = (float*)w;            w += (size_t)N * 64 * sizeof(float);
    float* Qh = (float*)w;            w += (size_t)N * 64 * sizeof(float);
    float* Pr = (float*)w;            w += (size_t)R * 64 * sizeof(float);
    float* Qr = (float*)w;            w += (size_t)R * 64 * sizeof(float);
    int*   deg    = (int*)w;          w += (size_t)N * sizeof(int);
    int*   incl   = (int*)w;          w += (size_t)N * sizeof(int);
    int*   offs   = (int*)w;          w += (size_t)N * sizeof(int);
    int*   cursor = (int*)w;          w += (size_t)N * sizeof(int);
    int*   bsums  = (int*)w;          w += 256 * sizeof(int);
    unsigned int* shr = (unsigned int*)w;  w += (size_t)E * sizeof(unsigned int);

    // 1) projection tables (linear decomposition of both per-edge GEMMs)
    int gN = (N + 63) / 64;
    int gR = (R + 63) / 64;
    gemm_nt64<<<gN, 256, 0, stream>>>(emb_ent, N, attn_W, 192, 0,   Pt);
    gemm_nt64<<<gN, 256, 0, stream>>>(emb_ent, N, attn_W, 192, 64,  Ph);
    gemm_nt64<<<gN, 256, 0, stream>>>(emb_ent, N, aggr_W, 128, 0,   Qh);
    gemm_nt64<<<gR, 256, 0, stream>>>(emb_rel, R, attn_W, 192, 128, Pr);
    gemm_nt64<<<gR, 256, 0, stream>>>(emb_rel, R, aggr_W, 128, 64,  Qr);

    // 2) CSR by tail
    hipMemsetAsync(deg, 0, (size_t)N * sizeof(int), stream);
    hist_kernel<<<(E + 255) / 256, 256, 0, stream>>>(tail, E, deg);
    int nb = (N + 255) / 256;     // 196 for N=50000 (must be <= 256)
    scan_chunk<<<nb, 256, 0, stream>>>(deg, N, incl, bsums);
    scan_tops<<<1, 256, 0, stream>>>(bsums, nb);
    scan_final<<<nb, 256, 0, stream>>>(deg, incl, bsums, N, offs, cursor);
    place_kernel<<<(E + 255) / 256, 256, 0, stream>>>(head, tail, rel, E, cursor, shr);

    // 3) per-node online-softmax aggregation (one wave per node)
    ingram_main<<<(N + 3) / 4, 256, 0, stream>>>(Pt, Ph, Qh, Pr, Qr, deg, offs, shr,
                                                 attn_b, attn_vec, aggr_b,
                                                 (float*)d_out, N);
}